// Round 5
// baseline (450.768 us; speedup 1.0000x reference)
//
#include <hip/hip_runtime.h>
#include <hip/hip_bf16.h>
#include <stdint.h>

// MHSA on MI355X: B=2, S=2048, H=2048, NH=16, D=128. Round 9 (resubmit; round
// 10 bench slot — previous attempt died to container infra, no counters).
//   qkv: per-block MFMA operand swap for Q/K tiles (MFMAH(b,a) -> lane holds
//   fixed s + 4 consecutive d) so Q/K epilogues store aligned uint2 (32 stores
//   per thread vs 128 scalar f16) -- kills the 1.6x write amplification seen
//   in WRITE_SIZE (81MB vs 50MB ideal). V tiles keep original order (already
//   vectorized). 8-phase core unchanged otherwise.
//   attn: T5 setprio around QK/PV MFMA clusters; T13-style skip of O-rescale
//   when all alphas == 1 (max stable after first tiles; exact skip).
//   out_gemm/packs unchanged.
// ws: Xp | Wq..Wo | Qd Kd Vt | AOp = 117.4 MB.

#define Bc 2
#define Sc 2048
#define Hc 2048
#define NHc 16
#define Dc 128
#define Mc 4096

typedef unsigned short ushortT;
typedef float f32x4 __attribute__((ext_vector_type(4)));
typedef _Float16 f16x8 __attribute__((ext_vector_type(8)));

#define MFMAH(a, b, c) __builtin_amdgcn_mfma_f32_16x16x32_f16((a), (b), (c), 0, 0, 0)
#define MF_AB(a, b, c) MFMAH((a), (b), (c))
#define MF_BA(a, b, c) MFMAH((b), (a), (c))

static __device__ __forceinline__ ushortT f2h(float x) {
    _Float16 h = (_Float16)x;
    return __builtin_bit_cast(unsigned short, h);
}

static __device__ __forceinline__ void load_lds16(const ushortT* g, ushortT* l) {
    __builtin_amdgcn_global_load_lds(
        (__attribute__((address_space(1))) void*)(g),
        (__attribute__((address_space(3))) void*)(l), 16, 0, 0);
}

// ---------------------------------------------------------------------------
// pack_a: X [4096][2048] fp32 -> Xp tiled fp16. grid (32 mt, 32 kt) x 256.
// ---------------------------------------------------------------------------
__global__ __launch_bounds__(256) void pack_a(
    const float* __restrict__ src, ushortT* __restrict__ dst)
{
    const int mt = blockIdx.x, kt = blockIdx.y;
    const int t = threadIdx.x;
    const int kq = t & 15;
    const int r0 = t >> 4;
    ushortT* tile = dst + ((size_t)(mt * 32 + kt)) * 8192;
#pragma unroll
    for (int rr = 0; rr < 8; ++rr) {
        const int row = r0 + rr * 16;
        const float4 v = *(const float4*)(src + (size_t)(mt * 128 + row) * Hc + kt * 64 + kq * 4);
        _Float16 h[4] = {(_Float16)v.x, (_Float16)v.y, (_Float16)v.z, (_Float16)v.w};
        const int gid = kq >> 1, halfg = kq & 1;
        const int gp = gid ^ (row & 7);
        *(uint2*)(tile + (size_t)row * 64 + gp * 8 + halfg * 4) = *(uint2*)h;
    }
}

// ---------------------------------------------------------------------------
// pack_b: W [k][n] fp32 -> B-operand tiled fp16. grid (16 nt, 32 kt, 4).
// ---------------------------------------------------------------------------
__global__ __launch_bounds__(256) void pack_b(
    const float* __restrict__ W0, const float* __restrict__ W1,
    const float* __restrict__ W2, const float* __restrict__ W3,
    ushortT* __restrict__ dst)
{
    const int nt = blockIdx.x, kt = blockIdx.y, which = blockIdx.z;
    const float* W = (which == 0) ? W0 : (which == 1) ? W1 : (which == 2) ? W2 : W3;
    const int t = threadIdx.x;
    const int n = t & 127;
    const int g0 = (t >> 7) * 4;
    ushortT* tile = dst + (size_t)which * 4194304 + ((size_t)(nt * 32 + kt)) * 8192;
#pragma unroll
    for (int gi = 0; gi < 4; ++gi) {
        const int g = g0 + gi;
        _Float16 h[8];
#pragma unroll
        for (int j = 0; j < 8; ++j)
            h[j] = (_Float16)W[(size_t)(kt * 64 + g * 8 + j) * Hc + nt * 128 + n];
        const int gp = g ^ (n & 7);
        *(uint4*)(tile + (size_t)n * 64 + gp * 8) = *(uint4*)h;
    }
}

// ---------------------------------------------------------------------------
// 128x128 m97-style GEMM core (round-5): 4 waves x 64x64 quadrant, BK=64.
// ---------------------------------------------------------------------------
#define GEMM_PROLOGUE()                                                        \
    __shared__ __align__(16) ushortT As[8192], Bs[8192];                       \
    const int tid = threadIdx.x, wv_ = tid >> 6, lane = tid & 63;              \
    const int lane16 = lane & 15, quad = lane >> 4;                            \
    const int quad4 = quad * 4;                                                \
    const int wm = (wv_ & 1) * 64, wn = (wv_ >> 1) * 64;                       \
    int aoff[4][2], boff[4][2];                                                \
    _Pragma("unroll") for (int mi = 0; mi < 4; ++mi)                           \
        _Pragma("unroll") for (int kf = 0; kf < 2; ++kf) {                     \
            const int ra = wm + mi * 16 + lane16;                              \
            aoff[mi][kf] = ra * 64 + (((kf * 4 + quad) ^ (ra & 7)) << 3);      \
            const int rb = wn + mi * 16 + lane16;                              \
            boff[mi][kf] = rb * 64 + (((kf * 4 + quad) ^ (rb & 7)) << 3);      \
        }                                                                      \
    f32x4 acc[4][4];                                                           \
    _Pragma("unroll") for (int i = 0; i < 4; ++i)                              \
        _Pragma("unroll") for (int j = 0; j < 4; ++j) {                        \
            acc[i][j][0] = 0.f; acc[i][j][1] = 0.f;                            \
            acc[i][j][2] = 0.f; acc[i][j][3] = 0.f; }                          \
    ushortT* asd = &As[wv_ * 2048];                                            \
    ushortT* bsd = &Bs[wv_ * 2048];

#define GEMM_KLOOP(at, bt)                                                     \
    for (int kt2 = 0; kt2 < 32; ++kt2) {                                       \
        _Pragma("unroll") for (int i = 0; i < 4; ++i) {                        \
            load_lds16(at + i * 512 + lane * 8, asd + i * 512);                \
            load_lds16(bt + i * 512 + lane * 8, bsd + i * 512);                \
        }                                                                      \
        at += 8192; bt += 8192;                                                \
        __syncthreads();                                                       \
        _Pragma("unroll") for (int kf = 0; kf < 2; ++kf) {                     \
            f16x8 a[4], b[4];                                                  \
            _Pragma("unroll") for (int mi = 0; mi < 4; ++mi)                   \
                a[mi] = *(const f16x8*)&As[aoff[mi][kf]];                      \
            _Pragma("unroll") for (int nj = 0; nj < 4; ++nj)                   \
                b[nj] = *(const f16x8*)&Bs[boff[nj][kf]];                      \
            _Pragma("unroll") for (int nj = 0; nj < 4; ++nj)                   \
                _Pragma("unroll") for (int mi = 0; mi < 4; ++mi)               \
                    acc[mi][nj] = MFMAH(a[mi], b[nj], acc[mi][nj]);            \
        }                                                                      \
        __syncthreads();                                                       \
    }

// ---------------------------------------------------------------------------
// 256x256 8-phase GEMM core. 512 threads = 8 waves (wr = wv>>2, wc = wv&3);
// per-wave output 128x64 = acc[8][4] f32x4. K = 2048 -> 32 steps of BK=64.
// MF = MF_AB (acc: row=m on quad4+r, col=n on lane16)
//    | MF_BA (acc: row=n on quad4+r, col=m on lane16).
// ---------------------------------------------------------------------------
#define G256_PROLOGUE()                                                        \
    __shared__ __align__(16) ushortT LA[2][2][8192];                           \
    __shared__ __align__(16) ushortT LB[2][2][8192];                           \
    const int tid = threadIdx.x, wv_ = tid >> 6, lane = tid & 63;              \
    const int lane16 = lane & 15, quad = lane >> 4, quad4 = (lane >> 4) * 4;   \
    const int wr = wv_ >> 2, wc = wv_ & 3;                                     \
    const ushortT* LAr = &LA[0][0][0] + wr * 8192;                             \
    const ushortT* LBr = &LB[0][0][0] + (wc >> 1) * 8192;                      \
    int oA[2][4][2], oB[4][2];                                                 \
    _Pragma("unroll") for (int h = 0; h < 2; ++h)                              \
        _Pragma("unroll") for (int mi = 0; mi < 4; ++mi)                       \
            _Pragma("unroll") for (int kf = 0; kf < 2; ++kf) {                 \
                const int r_ = h * 64 + mi * 16 + lane16;                      \
                oA[h][mi][kf] = r_ * 64 + (((kf * 4 + quad) ^ (r_ & 7)) << 3); \
            }                                                                  \
    _Pragma("unroll") for (int nj = 0; nj < 4; ++nj)                           \
        _Pragma("unroll") for (int kf = 0; kf < 2; ++kf) {                     \
            const int r_ = (wc & 1) * 64 + nj * 16 + lane16;                   \
            oB[nj][kf] = r_ * 64 + (((kf * 4 + quad) ^ (r_ & 7)) << 3);        \
        }                                                                      \
    f32x4 acc[8][4];                                                           \
    _Pragma("unroll") for (int i = 0; i < 8; ++i)                              \
        _Pragma("unroll") for (int j = 0; j < 4; ++j) {                        \
            acc[i][j][0] = 0.f; acc[i][j][1] = 0.f;                            \
            acc[i][j][2] = 0.f; acc[i][j][3] = 0.f; }

// Stage one 16KB half-tile: per wave 2 x global_load_lds of 1KB.
#define STAGE(SRC, STEP, DST) do {                                             \
    const ushortT* g_ = (SRC) + (size_t)(STEP) * 8192;                         \
    ushortT* l_ = (DST) + wv_ * 1024;                                          \
    load_lds16(g_, l_);                                                        \
    load_lds16(g_ + 512, l_ + 512);                                            \
} while (0)

#define RD_A(S, H)                                                             \
    _Pragma("unroll") for (int mi = 0; mi < 4; ++mi)                           \
        _Pragma("unroll") for (int kf = 0; kf < 2; ++kf)                       \
            a[mi][kf] = *(const f16x8*)&LAr[(S) * 16384 + oA[H][mi][kf]];

#define RD_B(S)                                                                \
    _Pragma("unroll") for (int nj = 0; nj < 4; ++nj)                           \
        _Pragma("unroll") for (int kf = 0; kf < 2; ++kf)                       \
            b[nj][kf] = *(const f16x8*)&LBr[(S) * 16384 + oB[nj][kf]];

#define QUAD(MIB, NJB, MF)                                                     \
    _Pragma("unroll") for (int kf = 0; kf < 2; ++kf)                           \
        _Pragma("unroll") for (int mi = 0; mi < 4; ++mi)                       \
            _Pragma("unroll") for (int nj = 0; nj < 2; ++nj)                   \
                acc[(MIB) + mi][(NJB) + nj] =                                  \
                    MF(a[mi][kf], b[(NJB) + nj][kf], acc[(MIB) + mi][(NJB) + nj]);

#define PRE_MFMA()                                                             \
    __builtin_amdgcn_s_barrier();                                              \
    __builtin_amdgcn_s_setprio(1);

#define POST_MFMA()                                                            \
    __builtin_amdgcn_s_setprio(0);                                             \
    __builtin_amdgcn_s_barrier();

#define VMC6() asm volatile("s_waitcnt vmcnt(6)" ::: "memory")

#define MINS(x) ((x) < 31 ? (x) : 31)

#define G256_MAIN(AB0, AB1, BB0, BB1, MF)                                      \
    const ushortT* sA0 = (AB0) + wv_ * 1024 + lane * 8;                        \
    const ushortT* sA1 = (AB1) + wv_ * 1024 + lane * 8;                        \
    const ushortT* sB0 = (BB0) + wv_ * 1024 + lane * 8;                        \
    const ushortT* sB1 = (BB1) + wv_ * 1024 + lane * 8;                        \
    /* prologue: step0 (4 tiles) + step1 minus A1 (3 tiles); 14 loads/wave */  \
    STAGE(sB0, 0, &LB[0][0][0]); STAGE(sB1, 0, &LB[0][1][0]);                  \
    STAGE(sA0, 0, &LA[0][0][0]); STAGE(sA1, 0, &LA[0][1][0]);                  \
    STAGE(sB0, 1, &LB[1][0][0]); STAGE(sB1, 1, &LB[1][1][0]);                  \
    STAGE(sA0, 1, &LA[1][0][0]);                                               \
    VMC6();                                                                    \
    __builtin_amdgcn_s_barrier();                                              \
    _Pragma("clang loop unroll(disable)")                                      \
    for (int t = 0; t < 32; t += 2) {                                          \
        f16x8 a[4][2], b[4][2];                                                \
        /* P1: compute step t (slot0) Q(mi0-3,nj0-1) */                        \
        RD_A(0, 0); RD_B(0);                                                   \
        STAGE(sA1, t + 1, &LA[1][1][0]);                                       \
        PRE_MFMA(); QUAD(0, 0, MF); POST_MFMA();                               \
        /* P2: Q(mi0-3,nj2-3), regs held */                                    \
        STAGE(sB0, MINS(t + 2), &LB[0][0][0]);                                 \
        PRE_MFMA(); QUAD(0, 2, MF); POST_MFMA();                               \
        /* P3: Q(mi4-7,nj2-3) */                                               \
        RD_A(0, 1);                                                            \
        STAGE(sB1, MINS(t + 2), &LB[0][1][0]);                                 \
        PRE_MFMA(); QUAD(4, 2, MF); POST_MFMA();                               \
        /* P4: Q(mi4-7,nj0-1); vmcnt(6) -> slot1 (step t+1) fully landed */    \
        STAGE(sA0, MINS(t + 2), &LA[0][0][0]);                                 \
        VMC6();                                                                \
        PRE_MFMA(); QUAD(4, 0, MF); POST_MFMA();                               \
        /* P5: compute step t+1 (slot1) */                                     \
        RD_A(1, 0); RD_B(1);                                                   \
        STAGE(sA1, MINS(t + 2), &LA[0][1][0]);                                 \
        PRE_MFMA(); QUAD(0, 0, MF); POST_MFMA();                               \
        /* P6 */                                                               \
        STAGE(sB0, MINS(t + 3), &LB[1][0][0]);                                 \
        PRE_MFMA(); QUAD(0, 2, MF); POST_MFMA();                               \
        /* P7 */                                                               \
        RD_A(1, 1);                                                            \
        STAGE(sB1, MINS(t + 3), &LB[1][1][0]);                                 \
        PRE_MFMA(); QUAD(4, 2, MF); POST_MFMA();                               \
        /* P8: vmcnt(6) -> slot0 (step t+2) fully landed */                    \
        STAGE(sA0, MINS(t + 3), &LA[1][0][0]);                                 \
        VMC6();                                                                \
        PRE_MFMA(); QUAD(4, 0, MF); POST_MFMA();                               \
    }

// ---------------------------------------------------------------------------
// Fused QKV projection, 256x256 tiles over merged N=6144. grid = 384 1-D.
// Q/K blocks run the operand-swapped core (lane16 = s, quad4+r = 4 consecutive
// d) so epilogues vector-store uint2. V keeps original order.
// ---------------------------------------------------------------------------
__global__ __launch_bounds__(512, 2) void qkv_gemm256(
    const ushortT* __restrict__ Xp, const ushortT* __restrict__ Wall,
    const float* __restrict__ bq, const float* __restrict__ bk,
    const float* __restrict__ bv,
    ushortT* __restrict__ Qd, ushortT* __restrict__ Kd, ushortT* __restrict__ Vt)
{
    const int id = blockIdx.x;                 // 0..383, nwg%8==0 -> bijective
    const int swz = (id & 7) * 48 + (id >> 3); // XCD-grouped
    const int mt = swz & 15;                   // 0..15 (256-row tiles)
    const int bn = swz >> 4;                   // 0..23 (256-col tiles over 6144)
    const int which = bn >> 3, bnw = bn & 7;
    const ushortT* Ab0 = Xp + (size_t)((2 * mt + 0) * 32) * 8192;
    const ushortT* Ab1 = Xp + (size_t)((2 * mt + 1) * 32) * 8192;
    const ushortT* Wp  = Wall + (size_t)which * 4194304;
    const ushortT* Bb0 = Wp + (size_t)((bnw * 2 + 0) * 32) * 8192;
    const ushortT* Bb1 = Wp + (size_t)((bnw * 2 + 1) * 32) * 8192;
    const float* bias = (which == 0) ? bq : (which == 1) ? bk : bv;

    G256_PROLOGUE();

    const float QS = 0.08838834764831845f * 1.4426950408889634f; // 1/sqrt(D)*log2e

    if (which == 2) {
        // ---- V: original operand order (quad4+r = 4 consecutive s) ----
        G256_MAIN(Ab0, Ab1, Bb0, Bb1, MF_AB);
        asm volatile("s_waitcnt vmcnt(0)" ::: "memory");
#pragma unroll
        for (int nj = 0; nj < 4; ++nj) {
            const int colm = bnw * 256 + wc * 64 + nj * 16 + lane16;
            const float bb2 = bias[colm];
            const int dd = colm & 127;
            const int hh = colm >> 7;
#pragma unroll
            for (int mi = 0; mi < 8; ++mi) {
                const int m0 = mt * 256 + wr * 128 + mi * 16 + quad4;  // r=0 row
                const int b = m0 >> 11, s0_ = m0 & 2047;
                const size_t bhb = (size_t)(b * NHc + hh) * (Sc * Dc);
                const int t2 = s0_ >> 6, sin0 = s0_ & 63;  // sin0 % 4 == 0
                uint2 u;
                u.x = (uint32_t)f2h(acc[mi][nj][0] + bb2) |
                      ((uint32_t)f2h(acc[mi][nj][1] + bb2) << 16);
                u.y = (uint32_t)f2h(acc[mi][nj][2] + bb2) |
                      ((uint32_t)f2h(acc[mi][nj][3] + bb2) << 16);
                *(uint2*)&Vt[bhb + (size_t)t2 * 8192 + dd * 64 +
                             (((sin0 >> 3) ^ (dd & 7)) << 3) + (sin0 & 7)] = u;
            }
        }
    } else {
        // ---- Q/K: swapped order (lane16 = s, quad4+r = 4 consecutive d) ----
        G256_MAIN(Ab0, Ab1, Bb0, Bb1, MF_BA);
        asm volatile("s_waitcnt vmcnt(0)" ::: "memory");
#pragma unroll
        for (int nj = 0; nj < 4; ++nj) {
            const int col0 = bnw * 256 + wc * 64 + nj * 16 + quad4;  // 4 consec d
            const float4 bv4 = *(const float4*)&bias[col0];
            const int dd0 = col0 & 127;
            const int hh = col0 >> 7;
#pragma unroll
            for (int mi = 0; mi < 8; ++mi) {
                const int m = mt * 256 + wr * 128 + mi * 16 + lane16;
                const int b = m >> 11, s = m & 2047;
                const size_t bhb = (size_t)(b * NHc + hh) * (Sc * Dc);
                float v0 = acc[mi][nj][0] + bv4.x;
                float v1 = acc[mi][nj][1] + bv4.y;
                float v2 = acc[mi][nj][2] + bv4.z;
                float v3 = acc[mi][nj][3] + bv4.w;
                if (which == 0) {
                    uint2 u;
                    u.x = (uint32_t)f2h(v0 * QS) | ((uint32_t)f2h(v1 * QS) << 16);
                    u.y = (uint32_t)f2h(v2 * QS) | ((uint32_t)f2h(v3 * QS) << 16);
                    *(uint2*)&Qd[bhb + (size_t)s * Dc + dd0] = u;
                } else {
                    // K tile image: [64 s][128 d], granule g=d>>3 ^ (s&7)
                    const int t2 = s >> 6, sin_ = s & 63;
                    uint2 u;
                    u.x = (uint32_t)f2h(v0) | ((uint32_t)f2h(v1) << 16);
                    u.y = (uint32_t)f2h(v2) | ((uint32_t)f2h(v3) << 16);
                    *(uint2*)&Kd[bhb + (size_t)t2 * 8192 + sin_ * 128 +
                                 (((dd0 >> 3) ^ (sin_ & 7)) << 3) + (dd0 & 7)] = u;
                }
            }
        }
    }
}

// ---------------------------------------------------------------------------
// Flash attention, transposed-S formulation. Round-9: setprio around MFMA
// clusters (T5) + skip O-rescale when all alphas == 1 (T13-style, exact).
// ---------------------------------------------------------------------------
__global__ __launch_bounds__(128, 2) void attn(
    const ushortT* __restrict__ Qd, const ushortT* __restrict__ Kt,
    const ushortT* __restrict__ Vt, ushortT* __restrict__ AOp)
{
    const int id = blockIdx.x;                 // 0..1023
    const int slot = id >> 3;                  // 0..127
    const int pair = (id & 7) + ((slot >> 5) << 3);  // 0..31
    const int qt = slot & 31;                  // 0..31 (64-row q tiles)
    const int hh = pair & 15, bb = pair >> 4;

    const ushortT* Qp  = Qd + ((size_t)(bb * NHc + hh)) * Sc * Dc;
    const ushortT* Kbh = Kt + ((size_t)(bb * NHc + hh)) * Sc * Dc;
    const ushortT* Vbh = Vt + ((size_t)(bb * NHc + hh)) * Sc * Dc;

    __shared__ __align__(16) ushortT Ks[8192];      // 64 kv x 128 d tile image
    __shared__ __align__(16) ushortT Vs[8192];      // 128 d x 64 kv tile image
    __shared__ __align__(16) ushortT Pbuf[2][2048]; // per-wave P [32 q][64 kv]

    const int tid = threadIdx.x, wv_ = tid >> 6, lane = tid & 63;
    const int lane16 = lane & 15, quad = lane >> 4;
    const int quad8 = quad * 8, quad4 = quad * 4;
    const int s0 = qt * 64 + wv_ * 32;

    f16x8 q[2][4];
#pragma unroll
    for (int nj = 0; nj < 2; ++nj)
#pragma unroll
        for (int kf = 0; kf < 4; ++kf)
            q[nj][kf] = *(const f16x8*)(Qp + (size_t)(s0 + nj * 16 + lane16) * Dc + kf * 32 + quad8);

    f32x4 o[8][2];
#pragma unroll
    for (int dj = 0; dj < 8; ++dj)
#pragma unroll
        for (int nj = 0; nj < 2; ++nj) { o[dj][nj][0] = 0.f; o[dj][nj][1] = 0.f; o[dj][nj][2] = 0.f; o[dj][nj][3] = 0.f; }

    float m_run[2] = {-1e30f, -1e30f}, l_run[2] = {0.f, 0.f};
    ushortT* Pw = Pbuf[wv_];

    for (int nt = 0; nt < 32; ++nt) {
        const ushortT* ktile = Kbh + (size_t)nt * 8192 + wv_ * 4096;
        const ushortT* vtile = Vbh + (size_t)nt * 8192 + wv_ * 4096;
#pragma unroll
        for (int i = 0; i < 8; ++i) {
            load_lds16(ktile + i * 512 + lane * 8, Ks + wv_ * 4096 + i * 512);
            load_lds16(vtile + i * 512 + lane * 8, Vs + wv_ * 4096 + i * 512);
        }
        __syncthreads();

        f32x4 sacc[4][2];
#pragma unroll
        for (int mi = 0; mi < 4; ++mi)
#pragma unroll
            for (int nj = 0; nj < 2; ++nj) { sacc[mi][nj][0] = 0.f; sacc[mi][nj][1] = 0.f; sacc[mi][nj][2] = 0.f; sacc[mi][nj][3] = 0.f; }
        __builtin_amdgcn_s_setprio(1);
#pragma unroll
        for (int kf = 0; kf < 4; ++kf) {
            f16x8 kb[4];
#pragma unroll
            for (int mi = 0; mi < 4; ++mi) {
                const int row = mi * 16 + lane16;
                kb[mi] = *(const f16x8*)&Ks[row * 128 + (((kf * 4 + quad) ^ (row & 7)) << 3)];
            }
#pragma unroll
            for (int mi = 0; mi < 4; ++mi)
#pragma unroll
                for (int nj = 0; nj < 2; ++nj)
                    sacc[mi][nj] = MFMAH(kb[mi], q[nj][kf], sacc[mi][nj]);
        }
        __builtin_amdgcn_s_setprio(0);

        float alpha_[2];
#pragma unroll
        for (int nj = 0; nj < 2; ++nj) {
            float mx = sacc[0][nj][0];
#pragma unroll
            for (int mi = 0; mi < 4; ++mi)
#pragma unroll
                for (int r = 0; r < 4; ++r) mx = fmaxf(mx, sacc[mi][nj][r]);
            mx = fmaxf(mx, __shfl_xor(mx, 16));
            mx = fmaxf(mx, __shfl_xor(mx, 32));
            const float mnew = fmaxf(m_run[nj], mx);
            alpha_[nj] = exp2f(m_run[nj] - mnew);
            m_run[nj] = mnew;
            float sum = 0.f;
#pragma unroll
            for (int mi = 0; mi < 4; ++mi)
#pragma unroll
                for (int r = 0; r < 4; ++r) {
                    const float p = exp2f(sacc[mi][nj][r] - mnew);
                    sacc[mi][nj][r] = p;
                    sum += p;
                }
            sum += __shfl_xor(sum, 16);
            sum += __shfl_xor(sum, 32);
            l_run[nj] = l_run[nj] * alpha_[nj] + sum;
            const int prow = nj * 16 + lane16;
#pragma unroll
            for (int mi = 0; mi < 4; ++mi) {
                uint2 u;
                u.x = (uint32_t)f2h(sacc[mi][nj][0]) | ((uint32_t)f2h(sacc[mi][nj][1]) << 16);
                u.y = (uint32_t)f2h(sacc[mi][nj][2]) | ((uint32_t)f2h(sacc[mi][nj][3]) << 16);
                const int g = mi * 2 + (quad >> 1);
                *(uint2*)&Pw[prow * 64 + ((g ^ (prow & 7)) << 3) + (quad & 1) * 4] = u;
            }
        }

        // rescale O only if some lane's max moved (wave-uniform branch)
        if (__ballot((alpha_[0] != 1.f) | (alpha_[1] != 1.f)) != 0ull) {
#pragma unroll
            for (int dj = 0; dj < 8; ++dj)
#pragma unroll
                for (int nj = 0; nj < 2; ++nj) {
                    const float av = alpha_[nj];
                    o[dj][nj][0] *= av; o[dj][nj][1] *= av;
                    o[dj][nj][2] *= av; o[dj][nj][3] *= av;
                }
        }

        __builtin_amdgcn_s_setprio(1);
#pragma unroll
        for (int kf2 = 0; kf2 < 2; ++kf2) {
            f16x8 pb[2];
#pragma unroll
            for (int nj = 0; nj < 2; ++nj) {
                const int row = nj * 16 + lane16;
                pb[nj] = *(const f16x8*)&Pw[row * 64 + (((kf2 * 4 + quad) ^ (row & 7)) << 3)];
            }
#pragma unroll
            for (int dj = 0; dj < 8; ++dj) {
                const int row = dj * 16 + lane16;
                const f16x8 vb = *(const f16x8*)&Vs[row * 64 + (((kf2 * 4 + quad) ^ (row & 7)) << 3)];
#pragma unroll
                for (int nj = 0; nj < 2; ++nj)
                    o[dj][nj] = MFMAH(vb, pb[nj], o[dj][nj]);
            }
        }
        __builtin_amdgcn_s_setprio(0);
        __syncthreads();
    }

#pragma unroll
    for (int nj = 0; nj < 2; ++nj) {
        const float inv = 1.f / l_run[nj];
        const int m = bb * Sc + qt * 64 + wv_ * 32 + nj * 16 + lane16;
        const int mtile = m >> 7, rin = m & 127;
#pragma unroll
        for (int dj = 0; dj < 8; ++dj) {
            const int ktile = hh * 2 + (dj >> 2);
            const int cin0 = (dj & 3) * 16 + quad4;
            const int g = cin0 >> 3, e0 = cin0 & 7;
            uint2 u;
            u.x = (uint32_t)f2h(o[dj][nj][0] * inv) | ((uint32_t)f2h(o[dj][nj][1] * inv) << 16);
            u.y = (uint32_t)f2h(o[dj][nj][2] * inv) | ((uint32_t)f2h(o[dj][nj][3] * inv) << 16);
            *(uint2*)&AOp[((size_t)(mtile * 32 + ktile)) * 8192 + rin * 64 +
                          ((g ^ (rin & 7)) << 3) + e0] = u;
        }
    }
}

// ---------------------------------------------------------------------------
// Output projection: out = AO @ Wo + bo. 128x128 m97-structure, grid (16, 32).
// ---------------------------------------------------------------------------
__global__ __launch_bounds__(256) void out_gemm(
    const ushortT* __restrict__ AOp, const ushortT* __restrict__ Wop,
    const float* __restrict__ bo, float* __restrict__ out)
{
    const int nt = blockIdx.x;
    const int mt = blockIdx.y;

    GEMM_PROLOGUE();

    const ushortT* at = AOp + (size_t)(mt * 32) * 8192 + wv_ * 2048;
    const ushortT* bt = Wop + (size_t)(nt * 32) * 8192 + wv_ * 2048;
    GEMM_KLOOP(at, bt);

#pragma unroll
    for (int nj = 0; nj < 4; ++nj) {
        const int col = nt * 128 + wn + nj * 16 + lane16;
        const float bb = bo[col];
#pragma unroll
        for (int mi = 0; mi < 4; ++mi)
#pragma unroll
            for (int r = 0; r < 4; ++r) {
                const int m = mt * 128 + wm + mi * 16 + quad4 + r;
                out[(size_t)m * Hc + col] = acc[mi][nj][r] + bb;
            }
    }
}

// ---------------------------------------------------------------------------
extern "C" void kernel_launch(void* const* d_in, const int* in_sizes, int n_in,
                              void* d_out, int out_size, void* d_ws, size_t ws_size,
                              hipStream_t stream) {
    (void)in_sizes; (void)n_in; (void)out_size; (void)ws_size;

    const float* X  = (const float*)d_in[0];
    const float* Wq = (const float*)d_in[1];
    const float* bq = (const float*)d_in[2];
    const float* Wk = (const float*)d_in[3];
    const float* bk = (const float*)d_in[4];
    const float* Wv = (const float*)d_in[5];
    const float* bv = (const float*)d_in[6];
    const float* Wo = (const float*)d_in[7];
    const float* bo = (const float*)d_in[8];
    float* out = (float*)d_out;

    ushortT* ws = (ushortT*)d_ws;
    const size_t E = (size_t)Mc * Hc;      // 8388608
    const size_t WE = (size_t)Hc * Hc;     // 4194304
    ushortT* Xp   = ws;
    ushortT* Wall = Xp + E;
    ushortT* Qd   = Wall + 4 * WE;
    ushortT* Kd   = Qd + E;
    ushortT* Vtp  = Kd + E;
    ushortT* AOp  = Vtp + E;               // total 117.4 MB

    pack_a<<<dim3(32, 32), 256, 0, stream>>>(X, Xp);
    pack_b<<<dim3(16, 32, 4), 256, 0, stream>>>(Wq, Wk, Wv, Wo, Wall);
    qkv_gemm256<<<dim3(384), 512, 0, stream>>>(Xp, Wall, bq, bk, bv, Qd, Kd, Vtp);
    attn<<<dim3(1024), 128, 0, stream>>>(Qd, Kd, Vtp, AOp);
    out_gemm<<<dim3(16, 32), 256, 0, stream>>>(AOp, Wall + 3 * WE, bo, out);
}

// Round 7
// 430.202 us; speedup vs baseline: 1.0478x; 1.0478x over previous
//
#include <hip/hip_runtime.h>
#include <hip/hip_bf16.h>
#include <stdint.h>

// MHSA on MI355X: B=2, S=2048, H=2048, NH=16, D=128. Round 12.
//   Fix of round-11's stage-coverage bug: the re-spread schedule dropped
//   A0(t+3) -> LA[1][0] went stale after the prologue (absmax 0.281). P8 now
//   stages A0(t+3) (after P7's slot1 a47 reads) and waits VMC6 (14-8=6:
//   slot0(t+2) landed, {B0,B1,A0}(t+3) in flight = steady state). P4 VMC4
//   unchanged (slot1(t+1) landed). Full per-phase vmcnt ledger re-traced.
//   Reads stay spread m201-style: P1 a03+b01(12), P2 b23(4), P3 a47(8), P4 0.
//   pack_b float4-vectorized; out_gemm operand-swapped (float4 stores);
//   attn setprio + exact rescale-skip. pack_a unchanged.
// ws: Xp | Wq..Wo | Qd Kd Vt | AOp = 117.4 MB.

#define Bc 2
#define Sc 2048
#define Hc 2048
#define NHc 16
#define Dc 128
#define Mc 4096

typedef unsigned short ushortT;
typedef float f32x4 __attribute__((ext_vector_type(4)));
typedef _Float16 f16x8 __attribute__((ext_vector_type(8)));

#define MFMAH(a, b, c) __builtin_amdgcn_mfma_f32_16x16x32_f16((a), (b), (c), 0, 0, 0)
#define MF_AB(a, b, c) MFMAH((a), (b), (c))
#define MF_BA(a, b, c) MFMAH((b), (a), (c))

static __device__ __forceinline__ ushortT f2h(float x) {
    _Float16 h = (_Float16)x;
    return __builtin_bit_cast(unsigned short, h);
}

static __device__ __forceinline__ void load_lds16(const ushortT* g, ushortT* l) {
    __builtin_amdgcn_global_load_lds(
        (__attribute__((address_space(1))) void*)(g),
        (__attribute__((address_space(3))) void*)(l), 16, 0, 0);
}

// ---------------------------------------------------------------------------
// pack_a: X [4096][2048] fp32 -> Xp tiled fp16. grid (32 mt, 32 kt) x 256.
// ---------------------------------------------------------------------------
__global__ __launch_bounds__(256) void pack_a(
    const float* __restrict__ src, ushortT* __restrict__ dst)
{
    const int mt = blockIdx.x, kt = blockIdx.y;
    const int t = threadIdx.x;
    const int kq = t & 15;
    const int r0 = t >> 4;
    ushortT* tile = dst + ((size_t)(mt * 32 + kt)) * 8192;
#pragma unroll
    for (int rr = 0; rr < 8; ++rr) {
        const int row = r0 + rr * 16;
        const float4 v = *(const float4*)(src + (size_t)(mt * 128 + row) * Hc + kt * 64 + kq * 4);
        _Float16 h[4] = {(_Float16)v.x, (_Float16)v.y, (_Float16)v.z, (_Float16)v.w};
        const int gid = kq >> 1, halfg = kq & 1;
        const int gp = gid ^ (row & 7);
        *(uint2*)(tile + (size_t)row * 64 + gp * 8 + halfg * 4) = *(uint2*)h;
    }
}

// ---------------------------------------------------------------------------
// pack_b: W [k][n] fp32 -> B-operand tiled fp16. grid (16 nt, 32 kt, 4).
// Vectorized: thread owns 4 consecutive n x one k-granule (8 k); 8 float4
// loads + 4 uint4 stores.
// ---------------------------------------------------------------------------
__global__ __launch_bounds__(256) void pack_b(
    const float* __restrict__ W0, const float* __restrict__ W1,
    const float* __restrict__ W2, const float* __restrict__ W3,
    ushortT* __restrict__ dst)
{
    const int nt = blockIdx.x, kt = blockIdx.y, which = blockIdx.z;
    const float* W = (which == 0) ? W0 : (which == 1) ? W1 : (which == 2) ? W2 : W3;
    const int t = threadIdx.x;
    const int n0 = (t & 31) * 4;   // 0,4,...,124
    const int kg = t >> 5;         // 0..7 k-granule
    ushortT* tile = dst + (size_t)which * 4194304 + ((size_t)(nt * 32 + kt)) * 8192;
    _Float16 h[4][8];
#pragma unroll
    for (int j = 0; j < 8; ++j) {
        const float4 v = *(const float4*)&W[(size_t)(kt * 64 + kg * 8 + j) * Hc + nt * 128 + n0];
        h[0][j] = (_Float16)v.x; h[1][j] = (_Float16)v.y;
        h[2][j] = (_Float16)v.z; h[3][j] = (_Float16)v.w;
    }
#pragma unroll
    for (int i = 0; i < 4; ++i) {
        const int n = n0 + i;
        *(uint4*)(tile + (size_t)n * 64 + ((kg ^ (n & 7)) << 3)) = *(uint4*)h[i];
    }
}

// ---------------------------------------------------------------------------
// 128x128 m97-style GEMM core: 4 waves x 64x64 quadrant, BK=64.
// ---------------------------------------------------------------------------
#define GEMM_PROLOGUE()                                                        \
    __shared__ __align__(16) ushortT As[8192], Bs[8192];                       \
    const int tid = threadIdx.x, wv_ = tid >> 6, lane = tid & 63;              \
    const int lane16 = lane & 15, quad = lane >> 4;                            \
    const int quad4 = quad * 4;                                                \
    const int wm = (wv_ & 1) * 64, wn = (wv_ >> 1) * 64;                       \
    int aoff[4][2], boff[4][2];                                                \
    _Pragma("unroll") for (int mi = 0; mi < 4; ++mi)                           \
        _Pragma("unroll") for (int kf = 0; kf < 2; ++kf) {                     \
            const int ra = wm + mi * 16 + lane16;                              \
            aoff[mi][kf] = ra * 64 + (((kf * 4 + quad) ^ (ra & 7)) << 3);      \
            const int rb = wn + mi * 16 + lane16;                              \
            boff[mi][kf] = rb * 64 + (((kf * 4 + quad) ^ (rb & 7)) << 3);      \
        }                                                                      \
    f32x4 acc[4][4];                                                           \
    _Pragma("unroll") for (int i = 0; i < 4; ++i)                              \
        _Pragma("unroll") for (int j = 0; j < 4; ++j) {                        \
            acc[i][j][0] = 0.f; acc[i][j][1] = 0.f;                            \
            acc[i][j][2] = 0.f; acc[i][j][3] = 0.f; }                          \
    ushortT* asd = &As[wv_ * 2048];                                            \
    ushortT* bsd = &Bs[wv_ * 2048];

#define GEMM_KLOOP(at, bt, MF)                                                 \
    for (int kt2 = 0; kt2 < 32; ++kt2) {                                       \
        _Pragma("unroll") for (int i = 0; i < 4; ++i) {                        \
            load_lds16(at + i * 512 + lane * 8, asd + i * 512);                \
            load_lds16(bt + i * 512 + lane * 8, bsd + i * 512);                \
        }                                                                      \
        at += 8192; bt += 8192;                                                \
        __syncthreads();                                                       \
        _Pragma("unroll") for (int kf = 0; kf < 2; ++kf) {                     \
            f16x8 a[4], b[4];                                                  \
            _Pragma("unroll") for (int mi = 0; mi < 4; ++mi)                   \
                a[mi] = *(const f16x8*)&As[aoff[mi][kf]];                      \
            _Pragma("unroll") for (int nj = 0; nj < 4; ++nj)                   \
                b[nj] = *(const f16x8*)&Bs[boff[nj][kf]];                      \
            _Pragma("unroll") for (int nj = 0; nj < 4; ++nj)                   \
                _Pragma("unroll") for (int mi = 0; mi < 4; ++mi)               \
                    acc[mi][nj] = MF(a[mi], b[nj], acc[mi][nj]);               \
        }                                                                      \
        __syncthreads();                                                       \
    }

// ---------------------------------------------------------------------------
// 256x256 8-phase GEMM core. 512 threads = 8 waves (wr = wv>>2, wc = wv&3);
// per-wave output 128x64 = acc[8][4] f32x4. K = 2048 -> 32 steps of BK=64.
// Reads spread: P1 a03+b01 (12), P2 b23 (4), P3 a47 (8), P4 0 (mirror 5-8).
// Stages (8/iter = full coverage): P1 A1(t+1); P3 B0(t+2); P4 B1(t+2)+VMC4;
//   P5 A0,A1(t+2); P7 B0(t+3); P8 B1(t+3),A0(t+3)+VMC6.
// vmcnt ledger (loads, steady state): enter P1 with 6 {B0,B1,A0}(t+1);
//   P1 +2=8; P3 +2=10; P4 +2=12, VMC4 -> slot1(t+1) landed, 4 left;
//   P5 +4=8; P7 +2=10; P8 +4=14, VMC6 -> slot0(t+2) landed, 6 left. QED.
// ---------------------------------------------------------------------------
#define G256_PROLOGUE()                                                        \
    __shared__ __align__(16) ushortT LA[2][2][8192];                           \
    __shared__ __align__(16) ushortT LB[2][2][8192];                           \
    const int tid = threadIdx.x, wv_ = tid >> 6, lane = tid & 63;              \
    const int lane16 = lane & 15, quad = lane >> 4, quad4 = (lane >> 4) * 4;   \
    const int wr = wv_ >> 2, wc = wv_ & 3;                                     \
    const ushortT* LAr = &LA[0][0][0] + wr * 8192;                             \
    const ushortT* LBr = &LB[0][0][0] + (wc >> 1) * 8192;                      \
    int oA[2][4][2], oB[4][2];                                                 \
    _Pragma("unroll") for (int h = 0; h < 2; ++h)                              \
        _Pragma("unroll") for (int mi = 0; mi < 4; ++mi)                       \
            _Pragma("unroll") for (int kf = 0; kf < 2; ++kf) {                 \
                const int r_ = h * 64 + mi * 16 + lane16;                      \
                oA[h][mi][kf] = r_ * 64 + (((kf * 4 + quad) ^ (r_ & 7)) << 3); \
            }                                                                  \
    _Pragma("unroll") for (int nj = 0; nj < 4; ++nj)                           \
        _Pragma("unroll") for (int kf = 0; kf < 2; ++kf) {                     \
            const int r_ = (wc & 1) * 64 + nj * 16 + lane16;                   \
            oB[nj][kf] = r_ * 64 + (((kf * 4 + quad) ^ (r_ & 7)) << 3);        \
        }                                                                      \
    f32x4 acc[8][4];                                                           \
    _Pragma("unroll") for (int i = 0; i < 8; ++i)                              \
        _Pragma("unroll") for (int j = 0; j < 4; ++j) {                        \
            acc[i][j][0] = 0.f; acc[i][j][1] = 0.f;                            \
            acc[i][j][2] = 0.f; acc[i][j][3] = 0.f; }

// Stage one 16KB half-tile: per wave 2 x global_load_lds of 1KB.
#define STAGE(SRC, STEP, DST) do {                                             \
    const ushortT* g_ = (SRC) + (size_t)(STEP) * 8192;                         \
    ushortT* l_ = (DST) + wv_ * 1024;                                          \
    load_lds16(g_, l_);                                                        \
    load_lds16(g_ + 512, l_ + 512);                                            \
} while (0)

#define RD_A03(S)                                                              \
    _Pragma("unroll") for (int mi = 0; mi < 4; ++mi)                           \
        _Pragma("unroll") for (int kf = 0; kf < 2; ++kf)                       \
            a03[mi][kf] = *(const f16x8*)&LAr[(S) * 16384 + oA[0][mi][kf]];

#define RD_A47(S)                                                              \
    _Pragma("unroll") for (int mi = 0; mi < 4; ++mi)                           \
        _Pragma("unroll") for (int kf = 0; kf < 2; ++kf)                       \
            a47[mi][kf] = *(const f16x8*)&LAr[(S) * 16384 + oA[1][mi][kf]];

#define RD_B01(S)                                                              \
    _Pragma("unroll") for (int nj = 0; nj < 2; ++nj)                           \
        _Pragma("unroll") for (int kf = 0; kf < 2; ++kf)                       \
            b[nj][kf] = *(const f16x8*)&LBr[(S) * 16384 + oB[nj][kf]];

#define RD_B23(S)                                                              \
    _Pragma("unroll") for (int nj = 2; nj < 4; ++nj)                           \
        _Pragma("unroll") for (int kf = 0; kf < 2; ++kf)                       \
            b[nj][kf] = *(const f16x8*)&LBr[(S) * 16384 + oB[nj][kf]];

#define QUADQ(ARR, MIB, NJB, MF)                                               \
    _Pragma("unroll") for (int kf = 0; kf < 2; ++kf)                           \
        _Pragma("unroll") for (int mi = 0; mi < 4; ++mi)                       \
            _Pragma("unroll") for (int nj = 0; nj < 2; ++nj)                   \
                acc[(MIB) + mi][(NJB) + nj] =                                  \
                    MF(ARR[mi][kf], b[(NJB) + nj][kf], acc[(MIB) + mi][(NJB) + nj]);

#define PRE_MFMA()                                                             \
    __builtin_amdgcn_s_barrier();                                              \
    __builtin_amdgcn_s_setprio(1);

#define POST_MFMA()                                                            \
    __builtin_amdgcn_s_setprio(0);                                             \
    __builtin_amdgcn_s_barrier();

#define VMC6() asm volatile("s_waitcnt vmcnt(6)" ::: "memory")
#define VMC4() asm volatile("s_waitcnt vmcnt(4)" ::: "memory")

#define MINS(x) ((x) < 31 ? (x) : 31)

#define G256_MAIN(AB0, AB1, BB0, BB1, MF)                                      \
    const ushortT* sA0 = (AB0) + wv_ * 1024 + lane * 8;                        \
    const ushortT* sA1 = (AB1) + wv_ * 1024 + lane * 8;                        \
    const ushortT* sB0 = (BB0) + wv_ * 1024 + lane * 8;                        \
    const ushortT* sB1 = (BB1) + wv_ * 1024 + lane * 8;                        \
    /* prologue: step0 (4 tiles) + step1 minus A1 (3 tiles); 14 loads/wave */  \
    STAGE(sB0, 0, &LB[0][0][0]); STAGE(sB1, 0, &LB[0][1][0]);                  \
    STAGE(sA0, 0, &LA[0][0][0]); STAGE(sA1, 0, &LA[0][1][0]);                  \
    STAGE(sB0, 1, &LB[1][0][0]); STAGE(sB1, 1, &LB[1][1][0]);                  \
    STAGE(sA0, 1, &LA[1][0][0]);                                               \
    VMC6();                                                                    \
    __builtin_amdgcn_s_barrier();                                              \
    _Pragma("clang loop unroll(disable)")                                      \
    for (int t = 0; t < 32; t += 2) {                                          \
        f16x8 a03[4][2], a47[4][2], b[4][2];                                   \
        /* P1: step t (slot0) Q(mi0-3,nj0-1) */                                \
        RD_A03(0); RD_B01(0);                                                  \
        STAGE(sA1, t + 1, &LA[1][1][0]);                                       \
        PRE_MFMA(); QUADQ(a03, 0, 0, MF); POST_MFMA();                         \
        /* P2: Q(mi0-3,nj2-3) */                                               \
        RD_B23(0);                                                             \
        PRE_MFMA(); QUADQ(a03, 0, 2, MF); POST_MFMA();                         \
        /* P3: Q(mi4-7,nj2-3); slot0 B reads done at P2 */                     \
        RD_A47(0);                                                             \
        STAGE(sB0, MINS(t + 2), &LB[0][0][0]);                                 \
        PRE_MFMA(); QUADQ(a47, 4, 2, MF); POST_MFMA();                         \
        /* P4: Q(mi4-7,nj0-1); VMC4 -> slot1 (t+1) fully landed for P5 */      \
        STAGE(sB1, MINS(t + 2), &LB[0][1][0]);                                 \
        VMC4();                                                                \
        PRE_MFMA(); QUADQ(a47, 4, 0, MF); POST_MFMA();                         \
        /* P5: step t+1 (slot1); slot0 A reads done at P1/P3 */                \
        RD_A03(1); RD_B01(1);                                                  \
        STAGE(sA0, MINS(t + 2), &LA[0][0][0]);                                 \
        STAGE(sA1, MINS(t + 2), &LA[0][1][0]);                                 \
        PRE_MFMA(); QUADQ(a03, 0, 0, MF); POST_MFMA();                         \
        /* P6 */                                                               \
        RD_B23(1);                                                             \
        PRE_MFMA(); QUADQ(a03, 0, 2, MF); POST_MFMA();                         \
        /* P7 */                                                               \
        RD_A47(1);                                                             \
        STAGE(sB0, MINS(t + 3), &LB[1][0][0]);                                 \
        PRE_MFMA(); QUADQ(a47, 4, 2, MF); POST_MFMA();                         \
        /* P8: stage B1,A0(t+3) after slot1 reads; VMC6 -> slot0 (t+2) ready */\
        STAGE(sB1, MINS(t + 3), &LB[1][1][0]);                                 \
        STAGE(sA0, MINS(t + 3), &LA[1][0][0]);                                 \
        VMC6();                                                                \
        PRE_MFMA(); QUADQ(a47, 4, 0, MF); POST_MFMA();                         \
    }

// ---------------------------------------------------------------------------
// Fused QKV projection, 256x256 tiles over merged N=6144. grid = 384 1-D.
// Q/K blocks: operand-swapped core (lane16 = s, quad4+r = 4 consecutive d).
// ---------------------------------------------------------------------------
__global__ __launch_bounds__(512, 2) void qkv_gemm256(
    const ushortT* __restrict__ Xp, const ushortT* __restrict__ Wall,
    const float* __restrict__ bq, const float* __restrict__ bk,
    const float* __restrict__ bv,
    ushortT* __restrict__ Qd, ushortT* __restrict__ Kd, ushortT* __restrict__ Vt)
{
    const int id = blockIdx.x;                 // 0..383, nwg%8==0 -> bijective
    const int swz = (id & 7) * 48 + (id >> 3); // XCD-grouped
    const int mt = swz & 15;                   // 0..15 (256-row tiles)
    const int bn = swz >> 4;                   // 0..23 (256-col tiles over 6144)
    const int which = bn >> 3, bnw = bn & 7;
    const ushortT* Ab0 = Xp + (size_t)((2 * mt + 0) * 32) * 8192;
    const ushortT* Ab1 = Xp + (size_t)((2 * mt + 1) * 32) * 8192;
    const ushortT* Wp  = Wall + (size_t)which * 4194304;
    const ushortT* Bb0 = Wp + (size_t)((bnw * 2 + 0) * 32) * 8192;
    const ushortT* Bb1 = Wp + (size_t)((bnw * 2 + 1) * 32) * 8192;
    const float* bias = (which == 0) ? bq : (which == 1) ? bk : bv;

    G256_PROLOGUE();

    const float QS = 0.08838834764831845f * 1.4426950408889634f; // 1/sqrt(D)*log2e

    if (which == 2) {
        // ---- V: original operand order (quad4+r = 4 consecutive s) ----
        G256_MAIN(Ab0, Ab1, Bb0, Bb1, MF_AB);
        asm volatile("s_waitcnt vmcnt(0)" ::: "memory");
#pragma unroll
        for (int nj = 0; nj < 4; ++nj) {
            const int colm = bnw * 256 + wc * 64 + nj * 16 + lane16;
            const float bb2 = bias[colm];
            const int dd = colm & 127;
            const int hh = colm >> 7;
#pragma unroll
            for (int mi = 0; mi < 8; ++mi) {
                const int m0 = mt * 256 + wr * 128 + mi * 16 + quad4;  // r=0 row
                const int b = m0 >> 11, s0_ = m0 & 2047;
                const size_t bhb = (size_t)(b * NHc + hh) * (Sc * Dc);
                const int t2 = s0_ >> 6, sin0 = s0_ & 63;  // sin0 % 4 == 0
                uint2 u;
                u.x = (uint32_t)f2h(acc[mi][nj][0] + bb2) |
                      ((uint32_t)f2h(acc[mi][nj][1] + bb2) << 16);
                u.y = (uint32_t)f2h(acc[mi][nj][2] + bb2) |
                      ((uint32_t)f2h(acc[mi][nj][3] + bb2) << 16);
                *(uint2*)&Vt[bhb + (size_t)t2 * 8192 + dd * 64 +
                             (((sin0 >> 3) ^ (dd & 7)) << 3) + (sin0 & 7)] = u;
            }
        }
    } else {
        // ---- Q/K: swapped order (lane16 = s, quad4+r = 4 consecutive d) ----
        G256_MAIN(Ab0, Ab1, Bb0, Bb1, MF_BA);
        asm volatile("s_waitcnt vmcnt(0)" ::: "memory");
#pragma unroll
        for (int nj = 0; nj < 4; ++nj) {
            const int col0 = bnw * 256 + wc * 64 + nj * 16 + quad4;  // 4 consec d
            const float4 bv4 = *(const float4*)&bias[col0];
            const int dd0 = col0 & 127;
            const int hh = col0 >> 7;
#pragma unroll
            for (int mi = 0; mi < 8; ++mi) {
                const int m = mt * 256 + wr * 128 + mi * 16 + lane16;
                const int b = m >> 11, s = m & 2047;
                const size_t bhb = (size_t)(b * NHc + hh) * (Sc * Dc);
                float v0 = acc[mi][nj][0] + bv4.x;
                float v1 = acc[mi][nj][1] + bv4.y;
                float v2 = acc[mi][nj][2] + bv4.z;
                float v3 = acc[mi][nj][3] + bv4.w;
                if (which == 0) {
                    uint2 u;
                    u.x = (uint32_t)f2h(v0 * QS) | ((uint32_t)f2h(v1 * QS) << 16);
                    u.y = (uint32_t)f2h(v2 * QS) | ((uint32_t)f2h(v3 * QS) << 16);
                    *(uint2*)&Qd[bhb + (size_t)s * Dc + dd0] = u;
                } else {
                    // K tile image: [64 s][128 d], granule g=d>>3 ^ (s&7)
                    const int t2 = s >> 6, sin_ = s & 63;
                    uint2 u;
                    u.x = (uint32_t)f2h(v0) | ((uint32_t)f2h(v1) << 16);
                    u.y = (uint32_t)f2h(v2) | ((uint32_t)f2h(v3) << 16);
                    *(uint2*)&Kd[bhb + (size_t)t2 * 8192 + sin_ * 128 +
                                 (((dd0 >> 3) ^ (sin_ & 7)) << 3) + (dd0 & 7)] = u;
                }
            }
        }
    }
}

// ---------------------------------------------------------------------------
// Flash attention, transposed-S formulation (setprio + exact rescale skip).
// ---------------------------------------------------------------------------
__global__ __launch_bounds__(128, 2) void attn(
    const ushortT* __restrict__ Qd, const ushortT* __restrict__ Kt,
    const ushortT* __restrict__ Vt, ushortT* __restrict__ AOp)
{
    const int id = blockIdx.x;                 // 0..1023
    const int slot = id >> 3;                  // 0..127
    const int pair = (id & 7) + ((slot >> 5) << 3);  // 0..31
    const int qt = slot & 31;                  // 0..31 (64-row q tiles)
    const int hh = pair & 15, bb = pair >> 4;

    const ushortT* Qp  = Qd + ((size_t)(bb * NHc + hh)) * Sc * Dc;
    const ushortT* Kbh = Kt + ((size_t)(bb * NHc + hh)) * Sc * Dc;
    const ushortT* Vbh = Vt + ((size_t)(bb * NHc + hh)) * Sc * Dc;

    __shared__ __align__(16) ushortT Ks[8192];      // 64 kv x 128 d tile image
    __shared__ __align__(16) ushortT Vs[8192];      // 128 d x 64 kv tile image
    __shared__ __align__(16) ushortT Pbuf[2][2048]; // per-wave P [32 q][64 kv]

    const int tid = threadIdx.x, wv_ = tid >> 6, lane = tid & 63;
    const int lane16 = lane & 15, quad = lane >> 4;
    const int quad8 = quad * 8, quad4 = quad * 4;
    const int s0 = qt * 64 + wv_ * 32;

    f16x8 q[2][4];
#pragma unroll
    for (int nj = 0; nj < 2; ++nj)
#pragma unroll
        for (int kf = 0; kf < 4; ++kf)
            q[nj][kf] = *(const f16x8*)(Qp + (size_t)(s0 + nj * 16 + lane16) * Dc + kf * 32 + quad8);

    f32x4 o[8][2];
#pragma unroll
    for (int dj = 0; dj < 8; ++dj)
#pragma unroll
        for (int nj = 0; nj < 2; ++nj) { o[dj][nj][0] = 0.f; o[dj][nj][1] = 0.f; o[dj][nj][2] = 0.f; o[dj][nj][3] = 0.f; }

    float m_run[2] = {-1e30f, -1e30f}, l_run[2] = {0.f, 0.f};
    ushortT* Pw = Pbuf[wv_];

    for (int nt = 0; nt < 32; ++nt) {
        const ushortT* ktile = Kbh + (size_t)nt * 8192 + wv_ * 4096;
        const ushortT* vtile = Vbh + (size_t)nt * 8192 + wv_ * 4096;
#pragma unroll
        for (int i = 0; i < 8; ++i) {
            load_lds16(ktile + i * 512 + lane * 8, Ks + wv_ * 4096 + i * 512);
            load_lds16(vtile + i * 512 + lane * 8, Vs + wv_ * 4096 + i * 512);
        }
        __syncthreads();

        f32x4 sacc[4][2];
#pragma unroll
        for (int mi = 0; mi < 4; ++mi)
#pragma unroll
            for (int nj = 0; nj < 2; ++nj) { sacc[mi][nj][0] = 0.f; sacc[mi][nj][1] = 0.f; sacc[mi][nj][2] = 0.f; sacc[mi][nj][3] = 0.f; }
        __builtin_amdgcn_s_setprio(1);
#pragma unroll
        for (int kf = 0; kf < 4; ++kf) {
            f16x8 kb[4];
#pragma unroll
            for (int mi = 0; mi < 4; ++mi) {
                const int row = mi * 16 + lane16;
                kb[mi] = *(const f16x8*)&Ks[row * 128 + (((kf * 4 + quad) ^ (row & 7)) << 3)];
            }
#pragma unroll
            for (int mi = 0; mi < 4; ++mi)
#pragma unroll
                for (int nj = 0; nj < 2; ++nj)
                    sacc[mi][nj] = MFMAH(kb[mi], q[nj][kf], sacc[mi][nj]);
        }
        __builtin_amdgcn_s_setprio(0);

        float alpha_[2];
#pragma unroll
        for (int nj = 0; nj < 2; ++nj) {
            float mx = sacc[0][nj][0];
#pragma unroll
            for (int mi = 0; mi < 4; ++mi)
#pragma unroll
                for (int r = 0; r < 4; ++r) mx = fmaxf(mx, sacc[mi][nj][r]);
            mx = fmaxf(mx, __shfl_xor(mx, 16));
            mx = fmaxf(mx, __shfl_xor(mx, 32));
            const float mnew = fmaxf(m_run[nj], mx);
            alpha_[nj] = exp2f(m_run[nj] - mnew);
            m_run[nj] = mnew;
            float sum = 0.f;
#pragma unroll
            for (int mi = 0; mi < 4; ++mi)
#pragma unroll
                for (int r = 0; r < 4; ++r) {
                    const float p = exp2f(sacc[mi][nj][r] - mnew);
                    sacc[mi][nj][r] = p;
                    sum += p;
                }
            sum += __shfl_xor(sum, 16);
            sum += __shfl_xor(sum, 32);
            l_run[nj] = l_run[nj] * alpha_[nj] + sum;
            const int prow = nj * 16 + lane16;
#pragma unroll
            for (int mi = 0; mi < 4; ++mi) {
                uint2 u;
                u.x = (uint32_t)f2h(sacc[mi][nj][0]) | ((uint32_t)f2h(sacc[mi][nj][1]) << 16);
                u.y = (uint32_t)f2h(sacc[mi][nj][2]) | ((uint32_t)f2h(sacc[mi][nj][3]) << 16);
                const int g = mi * 2 + (quad >> 1);
                *(uint2*)&Pw[prow * 64 + ((g ^ (prow & 7)) << 3) + (quad & 1) * 4] = u;
            }
        }

        // rescale O only if some lane's max moved (wave-uniform branch)
        if (__ballot((alpha_[0] != 1.f) | (alpha_[1] != 1.f)) != 0ull) {
#pragma unroll
            for (int dj = 0; dj < 8; ++dj)
#pragma unroll
                for (int nj = 0; nj < 2; ++nj) {
                    const float av = alpha_[nj];
                    o[dj][nj][0] *= av; o[dj][nj][1] *= av;
                    o[dj][nj][2] *= av; o[dj][nj][3] *= av;
                }
        }

        __builtin_amdgcn_s_setprio(1);
#pragma unroll
        for (int kf2 = 0; kf2 < 2; ++kf2) {
            f16x8 pb[2];
#pragma unroll
            for (int nj = 0; nj < 2; ++nj) {
                const int row = nj * 16 + lane16;
                pb[nj] = *(const f16x8*)&Pw[row * 64 + (((kf2 * 4 + quad) ^ (row & 7)) << 3)];
            }
#pragma unroll
            for (int dj = 0; dj < 8; ++dj) {
                const int row = dj * 16 + lane16;
                const f16x8 vb = *(const f16x8*)&Vs[row * 64 + (((kf2 * 4 + quad) ^ (row & 7)) << 3)];
#pragma unroll
                for (int nj = 0; nj < 2; ++nj)
                    o[dj][nj] = MFMAH(vb, pb[nj], o[dj][nj]);
            }
        }
        __builtin_amdgcn_s_setprio(0);
        __syncthreads();
    }

#pragma unroll
    for (int nj = 0; nj < 2; ++nj) {
        const float inv = 1.f / l_run[nj];
        const int m = bb * Sc + qt * 64 + wv_ * 32 + nj * 16 + lane16;
        const int mtile = m >> 7, rin = m & 127;
#pragma unroll
        for (int dj = 0; dj < 8; ++dj) {
            const int ktile = hh * 2 + (dj >> 2);
            const int cin0 = (dj & 3) * 16 + quad4;
            const int g = cin0 >> 3, e0 = cin0 & 7;
            uint2 u;
            u.x = (uint32_t)f2h(o[dj][nj][0] * inv) | ((uint32_t)f2h(o[dj][nj][1] * inv) << 16);
            u.y = (uint32_t)f2h(o[dj][nj][2] * inv) | ((uint32_t)f2h(o[dj][nj][3] * inv) << 16);
            *(uint2*)&AOp[((size_t)(mtile * 32 + ktile)) * 8192 + rin * 64 +
                          ((g ^ (rin & 7)) << 3) + e0] = u;
        }
    }
}

// ---------------------------------------------------------------------------
// Output projection: out = AO @ Wo + bo. 128x128 m97-structure, grid (16, 32).
// Operand-swapped: lane16 = m, quad4+r = 4 consecutive cols -> float4 stores.
// ---------------------------------------------------------------------------
__global__ __launch_bounds__(256) void out_gemm(
    const ushortT* __restrict__ AOp, const ushortT* __restrict__ Wop,
    const float* __restrict__ bo, float* __restrict__ out)
{
    const int nt = blockIdx.x;
    const int mt = blockIdx.y;

    GEMM_PROLOGUE();

    const ushortT* at = AOp + (size_t)(mt * 32) * 8192 + wv_ * 2048;
    const ushortT* bt = Wop + (size_t)(nt * 32) * 8192 + wv_ * 2048;
    GEMM_KLOOP(at, bt, MF_BA);

#pragma unroll
    for (int nj = 0; nj < 4; ++nj) {
        const int col0 = nt * 128 + wn + nj * 16 + quad4;
        const float4 bv4 = *(const float4*)&bo[col0];
#pragma unroll
        for (int mi = 0; mi < 4; ++mi) {
            const int m = mt * 128 + wm + mi * 16 + lane16;
            float4 v;
            v.x = acc[mi][nj][0] + bv4.x;
            v.y = acc[mi][nj][1] + bv4.y;
            v.z = acc[mi][nj][2] + bv4.z;
            v.w = acc[mi][nj][3] + bv4.w;
            *(float4*)&out[(size_t)m * Hc + col0] = v;
        }
    }
}

// ---------------------------------------------------------------------------
extern "C" void kernel_launch(void* const* d_in, const int* in_sizes, int n_in,
                              void* d_out, int out_size, void* d_ws, size_t ws_size,
                              hipStream_t stream) {
    (void)in_sizes; (void)n_in; (void)out_size; (void)ws_size;

    const float* X  = (const float*)d_in[0];
    const float* Wq = (const float*)d_in[1];
    const float* bq = (const float*)d_in[2];
    const float* Wk = (const float*)d_in[3];
    const float* bk = (const float*)d_in[4];
    const float* Wv = (const float*)d_in[5];
    const float* bv = (const float*)d_in[6];
    const float* Wo = (const float*)d_in[7];
    const float* bo = (const float*)d_in[8];
    float* out = (float*)d_out;

    ushortT* ws = (ushortT*)d_ws;
    const size_t E = (size_t)Mc * Hc;      // 8388608
    const size_t WE = (size_t)Hc * Hc;     // 4194304
    ushortT* Xp   = ws;
    ushortT* Wall = Xp + E;
    ushortT* Qd   = Wall + 4 * WE;
    ushortT* Kd   = Qd + E;
    ushortT* Vtp  = Kd + E;
    ushortT* AOp  = Vtp + E;               // total 117.4 MB

    pack_a<<<dim3(32, 32), 256, 0, stream>>>(X, Xp);
    pack_b<<<dim3(16, 32, 4), 256, 0, stream>>>(Wq, Wk, Wv, Wo, Wall);
    qkv_gemm256<<<dim3(384), 512, 0, stream>>>(Xp, Wall, bq, bk, bv, Qd, Kd, Vtp);
    attn<<<dim3(1024), 128, 0, stream>>>(Qd, Kd, Vtp, AOp);
    out_gemm<<<dim3(16, 32), 256, 0, stream>>>(AOp, Wall + 3 * WE, bo, out);
}